// Round 3
// baseline (8851.178 us; speedup 1.0000x reference)
//
#include <hip/hip_runtime.h>
#include <math.h>

constexpr int SEQ_L = 2048;
constexpr int EDIM  = 300;
constexpr int NCLS  = 20;
constexpr unsigned SENT = 0xFFA5A5A5u;  // NaN payload: unproducible by finite math

typedef float f32x4 __attribute__((ext_vector_type(4)));

// ---------------------------------------------------------------------------
// init: Hbuf[0] = h_0 = zeros; Hbuf[1..2048] = sentinel. (ws poisoned 0xAA.)
// Hbuf is (SEQ_L+1) x [2 dir][512] f32 = 2049*1024 dwords = 524544 uint4.
// ---------------------------------------------------------------------------
__global__ __launch_bounds__(256) void init_kernel(uint4* H) {
  const int NT = 513 * 256;
  int idx = blockIdx.x * blockDim.x + threadIdx.x;
  const uint4 z = {0u, 0u, 0u, 0u};
  const uint4 s = {SENT, SENT, SENT, SENT};
#pragma unroll
  for (int i = 0; i < 4; ++i) {
    int q = i * NT + idx;
    if (q < 524544) H[q] = (q < 256) ? z : s;
  }
}

// ---------------------------------------------------------------------------
// gi = x @ Wih^T + bih (+ bhh folded for r,z). grid (SEQ_L/8, 2), block 256.
// ---------------------------------------------------------------------------
__global__ __launch_bounds__(256) void gi_kernel(
    const int* __restrict__ seq, const float* __restrict__ emb,
    const float* __restrict__ Wih_f, const float* __restrict__ bih_f,
    const float* __restrict__ bhh_f,
    const float* __restrict__ Wih_b, const float* __restrict__ bih_b,
    const float* __restrict__ bhh_b,
    float* __restrict__ gi_f, float* __restrict__ gi_b) {
  const int d = blockIdx.y;
  const float* Wih = d ? Wih_b : Wih_f;
  const float* bih = d ? bih_b : bih_f;
  const float* bhh = d ? bhh_b : bhh_f;
  float* gi = d ? gi_b : gi_f;
  const int t0 = blockIdx.x * 8;
  const int tid = threadIdx.x;

  __shared__ float xs[8][304];

  for (int i = tid; i < 8 * 75; i += 256) {
    int tt = i / 75, u = i - tt * 75;
    int t = t0 + tt;
    int s = seq[d ? (SEQ_L - 1 - t) : t];
    const float4* p = reinterpret_cast<const float4*>(emb + (size_t)s * EDIM);
    float4 v = p[u];
    xs[tt][u * 4 + 0] = v.x; xs[tt][u * 4 + 1] = v.y;
    xs[tt][u * 4 + 2] = v.z; xs[tt][u * 4 + 3] = v.w;
  }
  __syncthreads();

  for (int rr = 0; rr < 6; ++rr) {
    int j = rr * 256 + tid;
    const float4* wrow = reinterpret_cast<const float4*>(Wih + (size_t)j * EDIM);
    float acc[8];
#pragma unroll
    for (int tt = 0; tt < 8; ++tt) acc[tt] = 0.0f;
    for (int q = 0; q < EDIM / 4; ++q) {
      float4 w = wrow[q];
#pragma unroll
      for (int tt = 0; tt < 8; ++tt)
        acc[tt] += w.x * xs[tt][4 * q] + w.y * xs[tt][4 * q + 1] +
                   w.z * xs[tt][4 * q + 2] + w.w * xs[tt][4 * q + 3];
    }
    float bb = bih[j] + (j < 1024 ? bhh[j] : 0.0f);
#pragma unroll
    for (int tt = 0; tt < 8; ++tt)
      gi[(size_t)(t0 + tt) * 1536 + j] = acc[tt] + bb;
  }
}

// ---------------------------------------------------------------------------
// Recurrence: 32 WGs x 512 thr. Proven R0 comm primitives (agent-scope
// atomic load poll / agent-scope store) — rounds 1-2 proved XCD-local
// exchange is SLOWER (RMW serialization at TCC + dual-store pushing lines
// to IC anyway). Structural change instead: in the row-split layout lane l
// only consumes h[l*8..+7], so EVERY LANE POLLS ITS OWN 8 dwords directly
// (4 pipelined u64 atomic loads; each dword its own sentinel). This deletes
// the LDS h-broadcast and BOTH __syncthreads: waves free-run, coupled only
// by data. Gates per-wave (verified bit-exact in R1/R2): intra-wave LDS
// transpose-reduce -> 4 shfls -> lanes 0-3 gate math -> 16B agent store.
// All arithmetic expressions/orders verbatim from the absmax-0.0 kernels.
// Hang-proof: store precedes next poll, no barriers, no circular waits.
// ---------------------------------------------------------------------------
__global__ __launch_bounds__(512, 2) void rnn_kernel(
    const float* __restrict__ Whh_f, const float* __restrict__ bhh_f,
    const float* __restrict__ Whh_b, const float* __restrict__ bhh_b,
    const float* __restrict__ gi_f, const float* __restrict__ gi_b,
    float* Hbuf) {  // [SEQ_L+1][2 dir][512]
  const int tid  = threadIdx.x;
  const int lane = tid & 63;
  const int w    = tid >> 6;           // wave 0..7
  const int blk  = blockIdx.x;         // 0..31
  const int dir  = blk >> 4;
  const int j0   = (blk & 15) * 32;    // WG's 32 h-outputs

  const float* Whh = dir ? Whh_b : Whh_f;
  const float* bhh = dir ? bhh_b : bhh_f;
  const float* gi  = dir ? gi_b : gi_f;

  alignas(16) __shared__ float part[8][12][68];

  // wave w, row r = g*4+jj -> Whh row g*512 + j0 + w*4 + jj; lane cols *8..+7
  f32x4 Wv[24];
#pragma unroll
  for (int g = 0; g < 3; ++g)
#pragma unroll
    for (int jj = 0; jj < 4; ++jj) {
      const f32x4* rp = reinterpret_cast<const f32x4*>(
                            Whh + (size_t)(g * 512 + j0 + w * 4 + jj) * 512) +
                        lane * 2;
      Wv[(g * 4 + jj) * 2]     = rp[0];
      Wv[(g * 4 + jj) * 2 + 1] = rp[1];
    }

  float bhn = 0.0f;
  if (lane < 4) bhn = bhh[1024 + j0 + w * 4 + lane];
  float hprev = 0.0f;  // lane jj<4 carries h for output j0+w*4+jj

  for (int t = 0; t < SEQ_L; ++t) {
    // gi prefetch: lane r=g*4+jj (r<12) loads gi[g*512 + j0 + w*4 + jj];
    // independent of h, issues before the poll and hides under it.
    float giv = 0.0f;
    if (lane < 12)
      giv = gi[(size_t)t * 1536 + (lane >> 2) * 512 + j0 + w * 4 + (lane & 3)];

    // direct per-lane poll of the 8 h-dwords THIS lane consumes (32B).
    // 4 independent u64 agent-scope atomic loads pipeline into one vmcnt
    // wait; each dword is its own validity flag. No LDS, no barrier.
    const unsigned long long* hp = reinterpret_cast<const unsigned long long*>(
        Hbuf + (size_t)t * 1024 + dir * 512 + lane * 8);
    unsigned long long p0, p1, p2, p3;
    for (;;) {
      p0 = __hip_atomic_load(hp + 0, __ATOMIC_RELAXED, __HIP_MEMORY_SCOPE_AGENT);
      p1 = __hip_atomic_load(hp + 1, __ATOMIC_RELAXED, __HIP_MEMORY_SCOPE_AGENT);
      p2 = __hip_atomic_load(hp + 2, __ATOMIC_RELAXED, __HIP_MEMORY_SCOPE_AGENT);
      p3 = __hip_atomic_load(hp + 3, __ATOMIC_RELAXED, __HIP_MEMORY_SCOPE_AGENT);
      unsigned bad =
          ((unsigned)p0 == SENT) | ((unsigned)(p0 >> 32) == SENT) |
          ((unsigned)p1 == SENT) | ((unsigned)(p1 >> 32) == SENT) |
          ((unsigned)p2 == SENT) | ((unsigned)(p2 >> 32) == SENT) |
          ((unsigned)p3 == SENT) | ((unsigned)(p3 >> 32) == SENT);
      if (__ballot(bad != 0u) == 0ull) break;
    }
    f32x4 h0, h1;
    h0.x = __uint_as_float((unsigned)p0);
    h0.y = __uint_as_float((unsigned)(p0 >> 32));
    h0.z = __uint_as_float((unsigned)p1);
    h0.w = __uint_as_float((unsigned)(p1 >> 32));
    h1.x = __uint_as_float((unsigned)p2);
    h1.y = __uint_as_float((unsigned)(p2 >> 32));
    h1.z = __uint_as_float((unsigned)p3);
    h1.w = __uint_as_float((unsigned)(p3 >> 32));

    float s_[12];
#pragma unroll
    for (int r = 0; r < 12; ++r) {
      f32x4 w0 = Wv[2 * r], w1 = Wv[2 * r + 1];
      s_[r] = w0.x * h0.x + w0.y * h0.y + w0.z * h0.z + w0.w * h0.w +
              w1.x * h1.x + w1.y * h1.y + w1.z * h1.z + w1.w * h1.w;
    }

    // intra-wave LDS transpose-reduce (identical order to baseline)
#pragma unroll
    for (int r = 0; r < 12; ++r) part[w][r][lane] = s_[r];
    __builtin_amdgcn_wave_barrier();
    float red = 0.0f;
    if (lane < 12) {
      const f32x4* rowp = reinterpret_cast<const f32x4*>(&part[w][lane][0]);
      f32x4 a4 = rowp[0];
#pragma unroll
      for (int q = 1; q < 16; ++q) a4 += rowp[q];
      red = (a4.x + a4.y) + (a4.z + a4.w);
    }
    __builtin_amdgcn_wave_barrier();

    // per-wave gates: wave w owns outputs j0+w*4 .. +3 (bit-exact R1/R2 path)
    float redf = red + ((lane < 8) ? giv : 0.0f);  // sr+ir / sz+iz (commutative)
    int qq = lane & 3;
    float v_r = __shfl(redf, qq, 64);
    float v_z = __shfl(redf, 4 + qq, 64);
    float v_n = __shfl(redf, 8 + qq, 64);
    float v_i = __shfl(giv, 8 + qq, 64);
    if (lane < 4) {
      float rr = 1.0f / (1.0f + __expf(-v_r));
      float zz = 1.0f / (1.0f + __expf(-v_z));
      float nn = tanhf(v_i + rr * (v_n + bhn));
      float hnew = (1.0f - zz) * nn + zz * hprev;
      hprev = hnew;
      // proven agent-scope store (device coherence point)
      __hip_atomic_store(
          Hbuf + (size_t)(t + 1) * 1024 + dir * 512 + j0 + w * 4 + lane, hnew,
          __ATOMIC_RELAXED, __HIP_MEMORY_SCOPE_AGENT);
    }
  }
}

// ---------------------------------------------------------------------------
// classifier: hid = relu(W1 @ [hf;hb] + b1); logits = W2 @ hid + b2; softmax
// ---------------------------------------------------------------------------
__global__ __launch_bounds__(1024) void cls_kernel(
    const float* __restrict__ Hfin,  // Hbuf slot SEQ_L: [dir][512]
    const float* __restrict__ W1, const float* __restrict__ b1,
    const float* __restrict__ W2, const float* __restrict__ b2,
    float* __restrict__ out) {
  __shared__ float hcat[1024];
  __shared__ float hid[512];
  __shared__ float logits[NCLS];
  const int tid = threadIdx.x;
  hcat[tid] = Hfin[tid];
  __syncthreads();

  const int lane = tid & 63, widx = tid >> 6;
  for (int rr = 0; rr < 32; ++rr) {
    int row = widx * 32 + rr;
    const float4* wrow = reinterpret_cast<const float4*>(W1 + (size_t)row * 1024);
    float acc = 0.0f;
#pragma unroll
    for (int c = 0; c < 4; ++c) {
      int k = c * 256 + lane * 4;
      float4 v = wrow[c * 64 + lane];
      acc += v.x * hcat[k] + v.y * hcat[k + 1] + v.z * hcat[k + 2] +
             v.w * hcat[k + 3];
    }
#pragma unroll
    for (int mask = 32; mask >= 1; mask >>= 1) acc += __shfl_xor(acc, mask, 64);
    if (lane == 0) hid[row] = fmaxf(acc + b1[row], 0.0f);
  }
  __syncthreads();

  if (tid < NCLS) {
    const float4* wrow = reinterpret_cast<const float4*>(W2 + (size_t)tid * 512);
    float acc = 0.0f;
    for (int q = 0; q < 128; ++q) {
      float4 v = wrow[q];
      int k = q * 4;
      acc += v.x * hid[k] + v.y * hid[k + 1] + v.z * hid[k + 2] +
             v.w * hid[k + 3];
    }
    logits[tid] = acc + b2[tid];
  }
  __syncthreads();

  if (tid == 0) {
    float m = -1e30f;
    for (int i = 0; i < NCLS; ++i) m = fmaxf(m, logits[i]);
    float s = 0.0f;
    float e[NCLS];
    for (int i = 0; i < NCLS; ++i) { e[i] = __expf(logits[i] - m); s += e[i]; }
    float inv = 1.0f / s;
    for (int i = 0; i < NCLS; ++i) out[i] = e[i] * inv;
  }
}

// ---------------------------------------------------------------------------
extern "C" void kernel_launch(void* const* d_in, const int* in_sizes, int n_in,
                              void* d_out, int out_size, void* d_ws,
                              size_t ws_size, hipStream_t stream) {
  (void)in_sizes; (void)n_in; (void)out_size; (void)ws_size;
  const int*   seq   = (const int*)d_in[0];
  const float* emb   = (const float*)d_in[1];
  const float* Wih_f = (const float*)d_in[2];
  const float* Whh_f = (const float*)d_in[3];
  const float* bih_f = (const float*)d_in[4];
  const float* bhh_f = (const float*)d_in[5];
  const float* Wih_b = (const float*)d_in[6];
  const float* Whh_b = (const float*)d_in[7];
  const float* bih_b = (const float*)d_in[8];
  const float* bhh_b = (const float*)d_in[9];
  const float* W1    = (const float*)d_in[10];
  const float* b1    = (const float*)d_in[11];
  const float* W2    = (const float*)d_in[12];
  const float* b2    = (const float*)d_in[13];
  float* out = (float*)d_out;

  float* gi_f = (float*)d_ws;                   // 2048*1536 f32 (12.6 MB)
  float* gi_b = gi_f + (size_t)SEQ_L * 1536;    // 12.6 MB
  float* Hbuf = gi_b + (size_t)SEQ_L * 1536;    // 2049*1024 f32 (8.4 MB)

  hipLaunchKernelGGL(init_kernel, dim3(513), dim3(256), 0, stream,
                     (uint4*)Hbuf);
  hipLaunchKernelGGL(gi_kernel, dim3(SEQ_L / 8, 2), dim3(256), 0, stream,
                     seq, emb, Wih_f, bih_f, bhh_f, Wih_b, bih_b, bhh_b,
                     gi_f, gi_b);
  hipLaunchKernelGGL(rnn_kernel, dim3(32), dim3(512), 0, stream,
                     Whh_f, bhh_f, Whh_b, bhh_b, gi_f, gi_b, Hbuf);
  hipLaunchKernelGGL(cls_kernel, dim3(1), dim3(1024), 0, stream,
                     Hbuf + (size_t)SEQ_L * 1024, W1, b1, W2, b2, out);
}

// Round 5
// 5163.540 us; speedup vs baseline: 1.7142x; 1.7142x over previous
//
#include <hip/hip_runtime.h>
#include <math.h>

constexpr int SEQ_L = 2048;
constexpr int EDIM  = 300;
constexpr int NCLS  = 20;
constexpr unsigned SENT = 0xFFA5A5A5u;  // NaN payload: unproducible by finite math

typedef float f32x4 __attribute__((ext_vector_type(4)));

// ---------------------------------------------------------------------------
// init: Hbuf[0] = h_0 = zeros; Hbuf[1..2048] = sentinel. (ws poisoned 0xAA.)
// Hbuf is (SEQ_L+1) x [2 dir][512] f32 = 2049*1024 dwords = 524544 uint4.
// ---------------------------------------------------------------------------
__global__ __launch_bounds__(256) void init_kernel(uint4* H) {
  const int NT = 513 * 256;
  int idx = blockIdx.x * blockDim.x + threadIdx.x;
  const uint4 z = {0u, 0u, 0u, 0u};
  const uint4 s = {SENT, SENT, SENT, SENT};
#pragma unroll
  for (int i = 0; i < 4; ++i) {
    int q = i * NT + idx;
    if (q < 524544) H[q] = (q < 256) ? z : s;
  }
}

// ---------------------------------------------------------------------------
// gi = x @ Wih^T + bih (+ bhh folded for r,z). grid (SEQ_L/8, 2), block 256.
// ---------------------------------------------------------------------------
__global__ __launch_bounds__(256) void gi_kernel(
    const int* __restrict__ seq, const float* __restrict__ emb,
    const float* __restrict__ Wih_f, const float* __restrict__ bih_f,
    const float* __restrict__ bhh_f,
    const float* __restrict__ Wih_b, const float* __restrict__ bih_b,
    const float* __restrict__ bhh_b,
    float* __restrict__ gi_f, float* __restrict__ gi_b) {
  const int d = blockIdx.y;
  const float* Wih = d ? Wih_b : Wih_f;
  const float* bih = d ? bih_b : bih_f;
  const float* bhh = d ? bhh_b : bhh_f;
  float* gi = d ? gi_b : gi_f;
  const int t0 = blockIdx.x * 8;
  const int tid = threadIdx.x;

  __shared__ float xs[8][304];

  for (int i = tid; i < 8 * 75; i += 256) {
    int tt = i / 75, u = i - tt * 75;
    int t = t0 + tt;
    int s = seq[d ? (SEQ_L - 1 - t) : t];
    const float4* p = reinterpret_cast<const float4*>(emb + (size_t)s * EDIM);
    float4 v = p[u];
    xs[tt][u * 4 + 0] = v.x; xs[tt][u * 4 + 1] = v.y;
    xs[tt][u * 4 + 2] = v.z; xs[tt][u * 4 + 3] = v.w;
  }
  __syncthreads();

  for (int rr = 0; rr < 6; ++rr) {
    int j = rr * 256 + tid;
    const float4* wrow = reinterpret_cast<const float4*>(Wih + (size_t)j * EDIM);
    float acc[8];
#pragma unroll
    for (int tt = 0; tt < 8; ++tt) acc[tt] = 0.0f;
    for (int q = 0; q < EDIM / 4; ++q) {
      float4 w = wrow[q];
#pragma unroll
      for (int tt = 0; tt < 8; ++tt)
        acc[tt] += w.x * xs[tt][4 * q] + w.y * xs[tt][4 * q + 1] +
                   w.z * xs[tt][4 * q + 2] + w.w * xs[tt][4 * q + 3];
    }
    float bb = bih[j] + (j < 1024 ? bhh[j] : 0.0f);
#pragma unroll
    for (int tt = 0; tt < 8; ++tt)
      gi[(size_t)(t0 + tt) * 1536 + j] = acc[tt] + bb;
  }
}

// ---------------------------------------------------------------------------
// Recurrence: 32 WGs x 512 thr. R4 = composition of the only two designs
// that are BOTH hardware-verified: R0's comm mechanics (wave-slice poll at
// 1 dword/lane — the only poll that costs ONE IC round trip per iteration;
// R3 proved multi-atomic-load polls serialize 4x — plus LDS h-broadcast and
// agent-scope store) and the R1/R2/R3 per-wave step structure (bit-exact
// absmax 0.0 three times): wave w's 12 reduced rows are r/z/n of its own 4
// outputs -> gates + 16B store inside the owning wave, no wave-0 serial
// section, hsh double-buffered so ONE __syncthreads per step. Race-freedom
// of the single barrier: a wave can only write hsh[(t+2)&1]==hsh[t&1] after
// passing barrier t+1, which requires all waves' step-t reads of hsh[t&1]
// to have completed. No circular waits: stores precede polls in program
// order; polls wait only on the previous timestep's slot.
// ---------------------------------------------------------------------------
__global__ __launch_bounds__(512, 2) void rnn_kernel(
    const float* __restrict__ Whh_f, const float* __restrict__ bhh_f,
    const float* __restrict__ Whh_b, const float* __restrict__ bhh_b,
    const float* __restrict__ gi_f, const float* __restrict__ gi_b,
    float* Hbuf) {  // [SEQ_L+1][2 dir][512]
  const int tid  = threadIdx.x;
  const int lane = tid & 63;
  const int w    = tid >> 6;           // wave 0..7
  const int blk  = blockIdx.x;         // 0..31
  const int dir  = blk >> 4;
  const int j0   = (blk & 15) * 32;    // WG's 32 h-outputs

  const float* Whh = dir ? Whh_b : Whh_f;
  const float* bhh = dir ? bhh_b : bhh_f;
  const float* gi  = dir ? gi_b : gi_f;

  alignas(16) __shared__ float hsh[2][512];   // double-buffered by t&1
  alignas(16) __shared__ float part[8][12][68];

  // wave w, row r = g*4+jj -> Whh row g*512 + j0 + w*4 + jj; lane cols *8..+7
  f32x4 Wv[24];
#pragma unroll
  for (int g = 0; g < 3; ++g)
#pragma unroll
    for (int jj = 0; jj < 4; ++jj) {
      const f32x4* rp = reinterpret_cast<const f32x4*>(
                            Whh + (size_t)(g * 512 + j0 + w * 4 + jj) * 512) +
                        lane * 2;
      Wv[(g * 4 + jj) * 2]     = rp[0];
      Wv[(g * 4 + jj) * 2 + 1] = rp[1];
    }

  float bhn = 0.0f;
  if (lane < 4) bhn = bhh[1024 + j0 + w * 4 + lane];
  float hprev = 0.0f;  // lane jj<4 carries h for output j0+w*4+jj

  const int pollOff = dir * 512 + w * 64 + lane;

  for (int t = 0; t < SEQ_L; ++t) {
    // gi prefetch: lane r=g*4+jj (r<12) loads gi[g*512 + j0 + w*4 + jj];
    // independent of h, issues before the poll and hides under it.
    float giv = 0.0f;
    if (lane < 12)
      giv = gi[(size_t)t * 1536 + (lane >> 2) * 512 + j0 + w * 4 + (lane & 3)];

    // R0-proven poll: own 64-dword slice of h_t, ONE atomic dword load per
    // iteration (each dword its own validity flag).
    const float* hp = Hbuf + (size_t)t * 1024 + pollOff;
    float hvp;
    for (;;) {
      hvp = __hip_atomic_load(hp, __ATOMIC_RELAXED, __HIP_MEMORY_SCOPE_AGENT);
      if (__ballot(__float_as_uint(hvp) == SENT) == 0ull) break;
    }
    hsh[t & 1][w * 64 + lane] = hvp;
    __syncthreads();  // the ONLY barrier per step (hsh double-buffered)

    const f32x4* hq = reinterpret_cast<const f32x4*>(&hsh[t & 1][lane * 8]);
    f32x4 h0 = hq[0], h1 = hq[1];

    float s_[12];
#pragma unroll
    for (int r = 0; r < 12; ++r) {
      f32x4 w0 = Wv[2 * r], w1 = Wv[2 * r + 1];
      s_[r] = w0.x * h0.x + w0.y * h0.y + w0.z * h0.z + w0.w * h0.w +
              w1.x * h1.x + w1.y * h1.y + w1.z * h1.z + w1.w * h1.w;
    }

    // intra-wave LDS transpose-reduce (identical order to baseline)
#pragma unroll
    for (int r = 0; r < 12; ++r) part[w][r][lane] = s_[r];
    __builtin_amdgcn_wave_barrier();
    float red = 0.0f;
    if (lane < 12) {
      const f32x4* rowp = reinterpret_cast<const f32x4*>(&part[w][lane][0]);
      f32x4 a4 = rowp[0];
#pragma unroll
      for (int q = 1; q < 16; ++q) a4 += rowp[q];
      red = (a4.x + a4.y) + (a4.z + a4.w);
    }
    __builtin_amdgcn_wave_barrier();

    // per-wave gates: wave w owns outputs j0+w*4 .. +3 (bit-exact R1-R3 path)
    float redf = red + ((lane < 8) ? giv : 0.0f);  // sr+ir / sz+iz (commutative)
    int qq = lane & 3;
    float v_r = __shfl(redf, qq, 64);
    float v_z = __shfl(redf, 4 + qq, 64);
    float v_n = __shfl(redf, 8 + qq, 64);
    float v_i = __shfl(giv, 8 + qq, 64);
    if (lane < 4) {
      float rr = 1.0f / (1.0f + __expf(-v_r));
      float zz = 1.0f / (1.0f + __expf(-v_z));
      float nn = tanhf(v_i + rr * (v_n + bhn));
      float hnew = (1.0f - zz) * nn + zz * hprev;
      hprev = hnew;
      // proven agent-scope store (device coherence point)
      __hip_atomic_store(
          Hbuf + (size_t)(t + 1) * 1024 + dir * 512 + j0 + w * 4 + lane, hnew,
          __ATOMIC_RELAXED, __HIP_MEMORY_SCOPE_AGENT);
    }
  }
}

// ---------------------------------------------------------------------------
// classifier: hid = relu(W1 @ [hf;hb] + b1); logits = W2 @ hid + b2; softmax
// ---------------------------------------------------------------------------
__global__ __launch_bounds__(1024) void cls_kernel(
    const float* __restrict__ Hfin,  // Hbuf slot SEQ_L: [dir][512]
    const float* __restrict__ W1, const float* __restrict__ b1,
    const float* __restrict__ W2, const float* __restrict__ b2,
    float* __restrict__ out) {
  __shared__ float hcat[1024];
  __shared__ float hid[512];
  __shared__ float logits[NCLS];
  const int tid = threadIdx.x;
  hcat[tid] = Hfin[tid];
  __syncthreads();

  const int lane = tid & 63, widx = tid >> 6;
  for (int rr = 0; rr < 32; ++rr) {
    int row = widx * 32 + rr;
    const float4* wrow = reinterpret_cast<const float4*>(W1 + (size_t)row * 1024);
    float acc = 0.0f;
#pragma unroll
    for (int c = 0; c < 4; ++c) {
      int k = c * 256 + lane * 4;
      float4 v = wrow[c * 64 + lane];
      acc += v.x * hcat[k] + v.y * hcat[k + 1] + v.z * hcat[k + 2] +
             v.w * hcat[k + 3];
    }
#pragma unroll
    for (int mask = 32; mask >= 1; mask >>= 1) acc += __shfl_xor(acc, mask, 64);
    if (lane == 0) hid[row] = fmaxf(acc + b1[row], 0.0f);
  }
  __syncthreads();

  if (tid < NCLS) {
    const float4* wrow = reinterpret_cast<const float4*>(W2 + (size_t)tid * 512);
    float acc = 0.0f;
    for (int q = 0; q < 128; ++q) {
      float4 v = wrow[q];
      int k = q * 4;
      acc += v.x * hid[k] + v.y * hid[k + 1] + v.z * hid[k + 2] +
             v.w * hid[k + 3];
    }
    logits[tid] = acc + b2[tid];
  }
  __syncthreads();

  if (tid == 0) {
    float m = -1e30f;
    for (int i = 0; i < NCLS; ++i) m = fmaxf(m, logits[i]);
    float s = 0.0f;
    float e[NCLS];
    for (int i = 0; i < NCLS; ++i) { e[i] = __expf(logits[i] - m); s += e[i]; }
    float inv = 1.0f / s;
    for (int i = 0; i < NCLS; ++i) out[i] = e[i] * inv;
  }
}

// ---------------------------------------------------------------------------
extern "C" void kernel_launch(void* const* d_in, const int* in_sizes, int n_in,
                              void* d_out, int out_size, void* d_ws,
                              size_t ws_size, hipStream_t stream) {
  (void)in_sizes; (void)n_in; (void)out_size; (void)ws_size;
  const int*   seq   = (const int*)d_in[0];
  const float* emb   = (const float*)d_in[1];
  const float* Wih_f = (const float*)d_in[2];
  const float* Whh_f = (const float*)d_in[3];
  const float* bih_f = (const float*)d_in[4];
  const float* bhh_f = (const float*)d_in[5];
  const float* Wih_b = (const float*)d_in[6];
  const float* Whh_b = (const float*)d_in[7];
  const float* bih_b = (const float*)d_in[8];
  const float* bhh_b = (const float*)d_in[9];
  const float* W1    = (const float*)d_in[10];
  const float* b1    = (const float*)d_in[11];
  const float* W2    = (const float*)d_in[12];
  const float* b2    = (const float*)d_in[13];
  float* out = (float*)d_out;

  float* gi_f = (float*)d_ws;                   // 2048*1536 f32 (12.6 MB)
  float* gi_b = gi_f + (size_t)SEQ_L * 1536;    // 12.6 MB
  float* Hbuf = gi_b + (size_t)SEQ_L * 1536;    // 2049*1024 f32 (8.4 MB)

  hipLaunchKernelGGL(init_kernel, dim3(513), dim3(256), 0, stream,
                     (uint4*)Hbuf);
  hipLaunchKernelGGL(gi_kernel, dim3(SEQ_L / 8, 2), dim3(256), 0, stream,
                     seq, emb, Wih_f, bih_f, bhh_f, Wih_b, bih_b, bhh_b,
                     gi_f, gi_b);
  hipLaunchKernelGGL(rnn_kernel, dim3(32), dim3(512), 0, stream,
                     Whh_f, bhh_f, Whh_b, bhh_b, gi_f, gi_b, Hbuf);
  hipLaunchKernelGGL(cls_kernel, dim3(1), dim3(1024), 0, stream,
                     Hbuf + (size_t)SEQ_L * 1024, W1, b1, W2, b2, out);
}

// Round 7
// 4361.203 us; speedup vs baseline: 2.0295x; 1.1840x over previous
//
#include <hip/hip_runtime.h>
#include <math.h>

constexpr int SEQ_L = 2048;
constexpr int EDIM  = 300;
constexpr int NCLS  = 20;
constexpr unsigned SENT = 0xFFA5A5A5u;  // NaN payload: unproducible by finite math

typedef float f32x4 __attribute__((ext_vector_type(4)));

// ---------------------------------------------------------------------------
// init: Hbuf[0] = h_0 = zeros; Hbuf[1..2048] = sentinel. (ws poisoned 0xAA.)
// Hbuf is (SEQ_L+1) x [2 dir][512] f32 = 2049*1024 dwords = 524544 uint4.
// ---------------------------------------------------------------------------
__global__ __launch_bounds__(256) void init_kernel(uint4* H) {
  const int NT = 513 * 256;
  int idx = blockIdx.x * blockDim.x + threadIdx.x;
  const uint4 z = {0u, 0u, 0u, 0u};
  const uint4 s = {SENT, SENT, SENT, SENT};
#pragma unroll
  for (int i = 0; i < 4; ++i) {
    int q = i * NT + idx;
    if (q < 524544) H[q] = (q < 256) ? z : s;
  }
}

// ---------------------------------------------------------------------------
// gi = x @ Wih^T + bih (+ bhh folded for r,z). grid (SEQ_L/8, 2), block 256.
// ---------------------------------------------------------------------------
__global__ __launch_bounds__(256) void gi_kernel(
    const int* __restrict__ seq, const float* __restrict__ emb,
    const float* __restrict__ Wih_f, const float* __restrict__ bih_f,
    const float* __restrict__ bhh_f,
    const float* __restrict__ Wih_b, const float* __restrict__ bih_b,
    const float* __restrict__ bhh_b,
    float* __restrict__ gi_f, float* __restrict__ gi_b) {
  const int d = blockIdx.y;
  const float* Wih = d ? Wih_b : Wih_f;
  const float* bih = d ? bih_b : bih_f;
  const float* bhh = d ? bhh_b : bhh_f;
  float* gi = d ? gi_b : gi_f;
  const int t0 = blockIdx.x * 8;
  const int tid = threadIdx.x;

  __shared__ float xs[8][304];

  for (int i = tid; i < 8 * 75; i += 256) {
    int tt = i / 75, u = i - tt * 75;
    int t = t0 + tt;
    int s = seq[d ? (SEQ_L - 1 - t) : t];
    const float4* p = reinterpret_cast<const float4*>(emb + (size_t)s * EDIM);
    float4 v = p[u];
    xs[tt][u * 4 + 0] = v.x; xs[tt][u * 4 + 1] = v.y;
    xs[tt][u * 4 + 2] = v.z; xs[tt][u * 4 + 3] = v.w;
  }
  __syncthreads();

  for (int rr = 0; rr < 6; ++rr) {
    int j = rr * 256 + tid;
    const float4* wrow = reinterpret_cast<const float4*>(Wih + (size_t)j * EDIM);
    float acc[8];
#pragma unroll
    for (int tt = 0; tt < 8; ++tt) acc[tt] = 0.0f;
    for (int q = 0; q < EDIM / 4; ++q) {
      float4 w = wrow[q];
#pragma unroll
      for (int tt = 0; tt < 8; ++tt)
        acc[tt] += w.x * xs[tt][4 * q] + w.y * xs[tt][4 * q + 1] +
                   w.z * xs[tt][4 * q + 2] + w.w * xs[tt][4 * q + 3];
    }
    float bb = bih[j] + (j < 1024 ? bhh[j] : 0.0f);
#pragma unroll
    for (int tt = 0; tt < 8; ++tt)
      gi[(size_t)(t0 + tt) * 1536 + j] = acc[tt] + bb;
  }
}

// ---------------------------------------------------------------------------
// Recurrence: EXACT R0 structure (best measured: 3687us rnn / 4085 total).
// Single change: the poll is a 4-deep PING-PONG OF THE PROVEN INTRINSIC.
// Four relaxed agent-scope atomic loads to the same address stay in flight;
// the loop checks them round-robin, re-issuing each after its check. The
// compiler's waitcnt pass tracks every load exactly and emits counted waits
// (use of s0 with s1..s3 newer outstanding -> s_waitcnt vmcnt(3)), giving
// a ~210cy sampling quantum instead of ~850cy (one IC RT) — R6's goal with
// ZERO inline asm and zero hand-counted vmcnt (R6's asm variant faulted:
// async-load dest aliasing + hand counts in a compiler-tracked loop).
// Same instruction as R0's poll -> stale reads impossible by the same
// argument; every iteration issues fresh loads -> termination unchanged.
// Worst case (compiler drains to vmcnt(0) per sample) degenerates to R0.
// ---------------------------------------------------------------------------
__global__ __launch_bounds__(512, 2) void rnn_kernel(
    const float* __restrict__ Whh_f, const float* __restrict__ bhh_f,
    const float* __restrict__ Whh_b, const float* __restrict__ bhh_b,
    const float* __restrict__ gi_f, const float* __restrict__ gi_b,
    float* Hbuf) {  // [SEQ_L+1][2 dir][512]
  const int tid  = threadIdx.x;
  const int lane = tid & 63;
  const int w    = tid >> 6;           // wave 0..7
  const int blk  = blockIdx.x;         // 0..31
  const int dir  = blk >> 4;
  const int j0   = (blk & 15) * 32;    // WG's 32 h-outputs

  const float* Whh = dir ? Whh_b : Whh_f;
  const float* bhh = dir ? bhh_b : bhh_f;
  const float* gi  = dir ? gi_b : gi_f;

  alignas(16) __shared__ float hsh[512];
  alignas(16) __shared__ float part[8][12][68];
  __shared__ float rsum[96];

  // wave w, row r = g*4+jj -> Whh row g*512 + j0 + w*4 + jj; lane cols *8..+7
  f32x4 Wv[24];
#pragma unroll
  for (int g = 0; g < 3; ++g)
#pragma unroll
    for (int jj = 0; jj < 4; ++jj) {
      const f32x4* rp = reinterpret_cast<const f32x4*>(
                            Whh + (size_t)(g * 512 + j0 + w * 4 + jj) * 512) +
                        lane * 2;
      Wv[(g * 4 + jj) * 2]     = rp[0];
      Wv[(g * 4 + jj) * 2 + 1] = rp[1];
    }

  const int jl = j0 + lane;  // meaningful for wave 0, lane<32
  float bhn = 0.0f;
  if (w == 0 && lane < 32) bhn = bhh[1024 + jl];
  float hprev = 0.0f;  // wave 0 lane L carries h_t[j0+L]

  const int pollOff = dir * 512 + w * 64 + lane;

  for (int t = 0; t < SEQ_L; ++t) {
    // gi prefetch (wave 0 only; independent of h, hides under poll) — R0.
    float ir = 0.f, iz = 0.f, inn = 0.f;
    if (w == 0 && lane < 32) {
      const float* git = gi + (size_t)t * 1536;
      ir  = git[jl];
      iz  = git[512 + jl];
      inn = git[1024 + jl];
    }

    // 4-deep ping-pong poll of own 64-dword slice (1 dword/lane, the R0
    // primitive). Compiler-counted waits give ~RT/4 sampling quantum.
    const float* hp = Hbuf + (size_t)t * 1024 + pollOff;
    float s0 = __hip_atomic_load(hp, __ATOMIC_RELAXED, __HIP_MEMORY_SCOPE_AGENT);
    float s1 = __hip_atomic_load(hp, __ATOMIC_RELAXED, __HIP_MEMORY_SCOPE_AGENT);
    float s2 = __hip_atomic_load(hp, __ATOMIC_RELAXED, __HIP_MEMORY_SCOPE_AGENT);
    float s3 = __hip_atomic_load(hp, __ATOMIC_RELAXED, __HIP_MEMORY_SCOPE_AGENT);
    float hvp;
    for (;;) {
      if (__ballot(__float_as_uint(s0) == SENT) == 0ull) { hvp = s0; break; }
      s0 = __hip_atomic_load(hp, __ATOMIC_RELAXED, __HIP_MEMORY_SCOPE_AGENT);
      if (__ballot(__float_as_uint(s1) == SENT) == 0ull) { hvp = s1; break; }
      s1 = __hip_atomic_load(hp, __ATOMIC_RELAXED, __HIP_MEMORY_SCOPE_AGENT);
      if (__ballot(__float_as_uint(s2) == SENT) == 0ull) { hvp = s2; break; }
      s2 = __hip_atomic_load(hp, __ATOMIC_RELAXED, __HIP_MEMORY_SCOPE_AGENT);
      if (__ballot(__float_as_uint(s3) == SENT) == 0ull) { hvp = s3; break; }
      s3 = __hip_atomic_load(hp, __ATOMIC_RELAXED, __HIP_MEMORY_SCOPE_AGENT);
    }
    hsh[w * 64 + lane] = hvp;
    __syncthreads();  // sync1: full h_t in LDS

    const f32x4* hq = reinterpret_cast<const f32x4*>(&hsh[lane * 8]);
    f32x4 h0 = hq[0], h1 = hq[1];

    float s_[12];
#pragma unroll
    for (int r = 0; r < 12; ++r) {
      f32x4 w0 = Wv[2 * r], w1 = Wv[2 * r + 1];
      s_[r] = w0.x * h0.x + w0.y * h0.y + w0.z * h0.z + w0.w * h0.w +
              w1.x * h1.x + w1.y * h1.y + w1.z * h1.z + w1.w * h1.w;
    }

    // intra-wave LDS transpose-reduce (proven pattern)
#pragma unroll
    for (int r = 0; r < 12; ++r) part[w][r][lane] = s_[r];
    __builtin_amdgcn_wave_barrier();
    if (lane < 12) {
      const f32x4* rowp = reinterpret_cast<const f32x4*>(&part[w][lane][0]);
      f32x4 a4 = rowp[0];
#pragma unroll
      for (int q = 1; q < 16; ++q) a4 += rowp[q];
      rsum[w * 12 + lane] = (a4.x + a4.y) + (a4.z + a4.w);
    }
    __syncthreads();  // sync2: rsum ready; also fences hsh reuse at t+1

    if (w == 0 && lane < 32) {
      int ww = lane >> 2, jj = lane & 3;
      float sr = rsum[ww * 12 + jj];
      float sz = rsum[ww * 12 + 4 + jj];
      float sn = rsum[ww * 12 + 8 + jj];
      float rr = 1.0f / (1.0f + __expf(-(ir + sr)));
      float zz = 1.0f / (1.0f + __expf(-(iz + sz)));
      float nn = tanhf(inn + rr * (sn + bhn));
      float hnew = (1.0f - zz) * nn + zz * hprev;
      hprev = hnew;
      // ONE coalesced 128B agent store (R5 lesson: store-event count on the
      // serial chain dominates; keep the funnel-to-one-wave design).
      __hip_atomic_store(Hbuf + (size_t)(t + 1) * 1024 + dir * 512 + jl, hnew,
                         __ATOMIC_RELAXED, __HIP_MEMORY_SCOPE_AGENT);
    }
  }
}

// ---------------------------------------------------------------------------
// classifier: hid = relu(W1 @ [hf;hb] + b1); logits = W2 @ hid + b2; softmax
// ---------------------------------------------------------------------------
__global__ __launch_bounds__(1024) void cls_kernel(
    const float* __restrict__ Hfin,  // Hbuf slot SEQ_L: [dir][512]
    const float* __restrict__ W1, const float* __restrict__ b1,
    const float* __restrict__ W2, const float* __restrict__ b2,
    float* __restrict__ out) {
  __shared__ float hcat[1024];
  __shared__ float hid[512];
  __shared__ float logits[NCLS];
  const int tid = threadIdx.x;
  hcat[tid] = Hfin[tid];
  __syncthreads();

  const int lane = tid & 63, widx = tid >> 6;
  for (int rr = 0; rr < 32; ++rr) {
    int row = widx * 32 + rr;
    const float4* wrow = reinterpret_cast<const float4*>(W1 + (size_t)row * 1024);
    float acc = 0.0f;
#pragma unroll
    for (int c = 0; c < 4; ++c) {
      int k = c * 256 + lane * 4;
      float4 v = wrow[c * 64 + lane];
      acc += v.x * hcat[k] + v.y * hcat[k + 1] + v.z * hcat[k + 2] +
             v.w * hcat[k + 3];
    }
#pragma unroll
    for (int mask = 32; mask >= 1; mask >>= 1) acc += __shfl_xor(acc, mask, 64);
    if (lane == 0) hid[row] = fmaxf(acc + b1[row], 0.0f);
  }
  __syncthreads();

  if (tid < NCLS) {
    const float4* wrow = reinterpret_cast<const float4*>(W2 + (size_t)tid * 512);
    float acc = 0.0f;
    for (int q = 0; q < 128; ++q) {
      float4 v = wrow[q];
      int k = q * 4;
      acc += v.x * hid[k] + v.y * hid[k + 1] + v.z * hid[k + 2] +
             v.w * hid[k + 3];
    }
    logits[tid] = acc + b2[tid];
  }
  __syncthreads();

  if (tid == 0) {
    float m = -1e30f;
    for (int i = 0; i < NCLS; ++i) m = fmaxf(m, logits[i]);
    float s = 0.0f;
    float e[NCLS];
    for (int i = 0; i < NCLS; ++i) { e[i] = __expf(logits[i] - m); s += e[i]; }
    float inv = 1.0f / s;
    for (int i = 0; i < NCLS; ++i) out[i] = e[i] * inv;
  }
}

// ---------------------------------------------------------------------------
extern "C" void kernel_launch(void* const* d_in, const int* in_sizes, int n_in,
                              void* d_out, int out_size, void* d_ws,
                              size_t ws_size, hipStream_t stream) {
  (void)in_sizes; (void)n_in; (void)out_size; (void)ws_size;
  const int*   seq   = (const int*)d_in[0];
  const float* emb   = (const float*)d_in[1];
  const float* Wih_f = (const float*)d_in[2];
  const float* Whh_f = (const float*)d_in[3];
  const float* bih_f = (const float*)d_in[4];
  const float* bhh_f = (const float*)d_in[5];
  const float* Wih_b = (const float*)d_in[6];
  const float* Whh_b = (const float*)d_in[7];
  const float* bih_b = (const float*)d_in[8];
  const float* bhh_b = (const float*)d_in[9];
  const float* W1    = (const float*)d_in[10];
  const float* b1    = (const float*)d_in[11];
  const float* W2    = (const float*)d_in[12];
  const float* b2    = (const float*)d_in[13];
  float* out = (float*)d_out;

  float* gi_f = (float*)d_ws;                   // 2048*1536 f32 (12.6 MB)
  float* gi_b = gi_f + (size_t)SEQ_L * 1536;    // 12.6 MB
  float* Hbuf = gi_b + (size_t)SEQ_L * 1536;    // 2049*1024 f32 (8.4 MB)

  hipLaunchKernelGGL(init_kernel, dim3(513), dim3(256), 0, stream,
                     (uint4*)Hbuf);
  hipLaunchKernelGGL(gi_kernel, dim3(SEQ_L / 8, 2), dim3(256), 0, stream,
                     seq, emb, Wih_f, bih_f, bhh_f, Wih_b, bih_b, bhh_b,
                     gi_f, gi_b);
  hipLaunchKernelGGL(rnn_kernel, dim3(32), dim3(512), 0, stream,
                     Whh_f, bhh_f, Whh_b, bhh_b, gi_f, gi_b, Hbuf);
  hipLaunchKernelGGL(cls_kernel, dim3(1), dim3(1024), 0, stream,
                     Hbuf + (size_t)SEQ_L * 1024, W1, b1, W2, b2, out);
}